// Round 2
// baseline (218.718 us; speedup 1.0000x reference)
//
#include <hip/hip_runtime.h>
#include <hip/hip_bf16.h>

#define S_DIM 128
#define R_DIM 256
#define CM    256
#define CH    32
#define CZ    128

using bf16x8 = __attribute__((ext_vector_type(8))) short;
using f32x4  = __attribute__((ext_vector_type(4))) float;

static __device__ __forceinline__ unsigned short f2bf(float f) {
    __hip_bfloat16 h = __float2bfloat16(f);
    return *reinterpret_cast<unsigned short*>(&h);
}

// ---------------------------------------------------------------------------
// Prep A: w12T [h=64][c=256] bf16  (h<32 -> w1 col h, h>=32 -> w2 col h-32)
// ---------------------------------------------------------------------------
__global__ __launch_bounds__(256)
void w12t_kernel(const float* __restrict__ w1, const float* __restrict__ w2,
                 __hip_bfloat16* __restrict__ w12T)
{
    const int idx = blockIdx.x * 256 + threadIdx.x;   // 64 blocks -> 16384
    const int h = idx >> 8, c = idx & 255;
    const float v = (h < 32) ? w1[c * CH + h] : w2[c * CH + (h - 32)];
    w12T[idx] = __float2bfloat16(v);
}

// ---------------------------------------------------------------------------
// Prep B: w_out [1024][128] f32 -> wT [z=128][k=1024] bf16
// ---------------------------------------------------------------------------
__global__ __launch_bounds__(256)
void wt_kernel(const float* __restrict__ w, __hip_bfloat16* __restrict__ wT)
{
    const int idx = blockIdx.x * 256 + threadIdx.x;   // 512 blocks
    const int k = idx >> 7, z = idx & 127;
    wT[z * 1024 + k] = __float2bfloat16(w[idx]);
}

// ---------------------------------------------------------------------------
// Prep C: recip of mask norm: 1 / (sum_s mask[s,i]*mask[s,j] + 1e-3)
// ---------------------------------------------------------------------------
__global__ __launch_bounds__(256)
void norm_kernel(const float* __restrict__ mask, float* __restrict__ recip)
{
    const int i = blockIdx.x, j = threadIdx.x;
    float acc = 0.f;
    for (int s = 0; s < S_DIM; ++s)
        acc += mask[s * R_DIM + i] * mask[s * R_DIM + j];
    recip[i * R_DIM + j] = 1.0f / (acc + 1e-3f);
}

// ---------------------------------------------------------------------------
// Kernel 1: LayerNorm (f32 regs) -> bf16 LDS tile -> MFMA 256->64 projection
// a_t/b_t layout: [r][h][s]  (s contiguous -> MFMA fragment loads are 16B)
// wg = 32 rows sharing one s; 4 waves; LDS X[32][256] bf16 XOR-swizzled.
// ---------------------------------------------------------------------------
__global__ __launch_bounds__(256)
void ln_proj_kernel(const float* __restrict__ m, const float* __restrict__ mask,
                    const float* __restrict__ ls, const float* __restrict__ lb,
                    const __hip_bfloat16* __restrict__ w12T,
                    const float* __restrict__ b1v, const float* __restrict__ b2v,
                    __hip_bfloat16* __restrict__ a_t, __hip_bfloat16* __restrict__ b_t)
{
    __shared__ unsigned short X[32 * 256];   // 16 KB
    const int tid  = threadIdx.x;
    const int wave = tid >> 6, lane = tid & 63;
    const int l16 = lane & 15, l4 = lane >> 4;
    const int wg = blockIdx.x;
    const int s  = wg >> 3, r0 = (wg & 7) * 32;   // 32 rows, all same s
    char* Xb = reinterpret_cast<char*>(X);

    const float4 sc = *reinterpret_cast<const float4*>(ls + lane * 4);
    const float4 bi = *reinterpret_cast<const float4*>(lb + lane * 4);

    for (int rep = 0; rep < 8; ++rep) {
        const int row = wave * 8 + rep;
        const float4 x = *reinterpret_cast<const float4*>(
            m + ((size_t)wg * 32 + row) * CM + lane * 4);
        float sum = x.x + x.y + x.z + x.w;
        float sq  = x.x * x.x + x.y * x.y + x.z * x.z + x.w * x.w;
        #pragma unroll
        for (int off = 32; off; off >>= 1) {
            sum += __shfl_xor(sum, off);
            sq  += __shfl_xor(sq, off);
        }
        const float mu = sum * (1.0f / CM);
        const float rs = rsqrtf(sq * (1.0f / CM) - mu * mu + 1e-5f);
        ushort4 o;
        o.x = f2bf((x.x - mu) * rs * sc.x + bi.x);
        o.y = f2bf((x.y - mu) * rs * sc.y + bi.y);
        o.z = f2bf((x.z - mu) * rs * sc.z + bi.z);
        o.w = f2bf((x.w - mu) * rs * sc.w + bi.w);
        const int byte = (row * 512 + lane * 8) ^ ((row & 7) << 4);
        *reinterpret_cast<ushort4*>(Xb + byte) = o;
    }
    __syncthreads();

    // MFMA: waves = 2 m-tiles x 2 (a|b) halves; each wave: 2 n-tiles x 8 k-steps
    const int wm = wave >> 1, wn = wave & 1;
    const f32x4 zero = {0.f, 0.f, 0.f, 0.f};
    f32x4 acc[2];
    acc[0] = zero; acc[1] = zero;
    const int arow = wm * 16 + l16;
    const int asw  = (arow & 7) << 4;
    const char* arb = Xb + arow * 512;
    const __hip_bfloat16* wbase = w12T + (size_t)(wn * 32 + l16) * CM + l4 * 8;

    #pragma unroll
    for (int kb = 0; kb < 8; ++kb) {
        const bf16x8 af = *reinterpret_cast<const bf16x8*>(arb + ((kb * 64 + l4 * 16) ^ asw));
        #pragma unroll
        for (int nt = 0; nt < 2; ++nt) {
            const bf16x8 bf = *reinterpret_cast<const bf16x8*>(wbase + nt * 16 * CM + kb * 32);
            acc[nt] = __builtin_amdgcn_mfma_f32_16x16x32_bf16(af, bf, acc[nt], 0, 0, 0);
        }
    }

    __hip_bfloat16* dst = wn ? b_t : a_t;
    const float*    bv  = wn ? b2v : b1v;
    #pragma unroll
    for (int nt = 0; nt < 2; ++nt) {
        const int h = nt * 16 + l16;         // local h within the 32-wide half
        const float bo = bv[h];
        #pragma unroll
        for (int t = 0; t < 4; ++t) {
            const int row = wm * 16 + l4 * 4 + t;   // C/D: row=(lane>>4)*4+reg
            const int r = r0 + row;
            const float v = (acc[nt][t] + bo) * mask[s * R_DIM + r];
            dst[(size_t)r * (CH * S_DIM) + h * S_DIM + s] = __float2bfloat16(v);
        }
    }
}

// ---------------------------------------------------------------------------
// Kernel 2: fused outer-product (K=S=128) + w_out projection (K=1024)
// one WG = 8 i's x 8 j's = 64 pairs; LDS holds 64x1024 bf16 outer tile.
// Phase 2: each wave owns 16 z-cols, loops all 4 m-tiles (wT read once/wg/z).
// ---------------------------------------------------------------------------
__global__ __launch_bounds__(512)
void fused_kernel(const __hip_bfloat16* __restrict__ a_t,
                  const __hip_bfloat16* __restrict__ b_t,
                  const __hip_bfloat16* __restrict__ wT,
                  const float* __restrict__ b_out,
                  const float* __restrict__ recip,
                  float* __restrict__ out)
{
    __shared__ __hip_bfloat16 outer_lds[64 * 1024];   // 128 KB
    const int tid  = threadIdx.x;
    const int wave = tid >> 6, lane = tid & 63;
    const int l16 = lane & 15, l4 = lane >> 4;
    const int i0 = blockIdx.y * 8, j0 = blockIdx.x * 8;
    char* ldsb = reinterpret_cast<char*>(outer_lds);

    // ---- phase 1: outer products, wave w owns i = i0+w, loops 8 j's ----
    {
        const int i = i0 + wave;
        const __hip_bfloat16* abase = a_t + (size_t)i * (CH * S_DIM) + l16 * S_DIM + l4 * 8;
        bf16x8 afr[2][4];
        #pragma unroll
        for (int ch = 0; ch < 2; ++ch)
            #pragma unroll
            for (int kk = 0; kk < 4; ++kk)
                afr[ch][kk] = *reinterpret_cast<const bf16x8*>(abase + ch * 16 * S_DIM + kk * 32);

        for (int jj = 0; jj < 8; ++jj) {
            const __hip_bfloat16* bbase = b_t + (size_t)(j0 + jj) * (CH * S_DIM) + l16 * S_DIM + l4 * 8;
            bf16x8 bfr[2][4];
            #pragma unroll
            for (int eh = 0; eh < 2; ++eh)
                #pragma unroll
                for (int kk = 0; kk < 4; ++kk)
                    bfr[eh][kk] = *reinterpret_cast<const bf16x8*>(bbase + eh * 16 * S_DIM + kk * 32);

            const f32x4 zero = {0.f, 0.f, 0.f, 0.f};
            f32x4 acc[2][2];
            acc[0][0] = zero; acc[0][1] = zero; acc[1][0] = zero; acc[1][1] = zero;
            #pragma unroll
            for (int kk = 0; kk < 4; ++kk) {
                acc[0][0] = __builtin_amdgcn_mfma_f32_16x16x32_bf16(afr[0][kk], bfr[0][kk], acc[0][0], 0, 0, 0);
                acc[0][1] = __builtin_amdgcn_mfma_f32_16x16x32_bf16(afr[0][kk], bfr[1][kk], acc[0][1], 0, 0, 0);
                acc[1][0] = __builtin_amdgcn_mfma_f32_16x16x32_bf16(afr[1][kk], bfr[0][kk], acc[1][0], 0, 0, 0);
                acc[1][1] = __builtin_amdgcn_mfma_f32_16x16x32_bf16(afr[1][kk], bfr[1][kk], acc[1][1], 0, 0, 0);
            }
            const int pair = wave * 8 + jj;
            char* rowb = ldsb + pair * 2048;
            const int sw = (pair & 7) << 4;       // XOR swizzle vs 2048B-stride conflicts
            #pragma unroll
            for (int ch = 0; ch < 2; ++ch)
                #pragma unroll
                for (int eh = 0; eh < 2; ++eh)
                    #pragma unroll
                    for (int t = 0; t < 4; ++t) {
                        const int c = ch * 16 + l4 * 4 + t;   // C/D: row=(lane>>4)*4+reg
                        const int e = eh * 16 + l16;          //      col=lane&15
                        const int byte = ((c * CH + e) * 2) ^ sw;
                        *reinterpret_cast<__hip_bfloat16*>(rowb + byte) = __float2bfloat16(acc[ch][eh][t]);
                    }
        }
    }
    __syncthreads();

    // ---- phase 2: [64 pairs x 1024] @ wT^T -> [64 x 128], + bias, * recip ----
    // wave owns z-cols [wave*16, wave*16+16); loops 4 m-tiles; wT frag loaded 1x
    {
        const f32x4 zero = {0.f, 0.f, 0.f, 0.f};
        f32x4 pacc[4];
        pacc[0] = zero; pacc[1] = zero; pacc[2] = zero; pacc[3] = zero;
        const __hip_bfloat16* wbase = wT + (size_t)(wave * 16 + l16) * 1024 + l4 * 8;

        for (int kb = 0; kb < 32; ++kb) {
            const bf16x8 bf = *reinterpret_cast<const bf16x8*>(wbase + kb * 32);
            #pragma unroll
            for (int mt = 0; mt < 4; ++mt) {
                const int row = mt * 16 + l16;
                const bf16x8 af = *reinterpret_cast<const bf16x8*>(
                    ldsb + row * 2048 + ((kb * 64 + l4 * 16) ^ ((row & 7) << 4)));
                pacc[mt] = __builtin_amdgcn_mfma_f32_16x16x32_bf16(af, bf, pacc[mt], 0, 0, 0);
            }
        }
        const int z = wave * 16 + l16;
        const float bo = b_out[z];
        #pragma unroll
        for (int mt = 0; mt < 4; ++mt) {
            #pragma unroll
            for (int t = 0; t < 4; ++t) {
                const int pair = mt * 16 + l4 * 4 + t;
                const int i = i0 + (pair >> 3), j = j0 + (pair & 7);
                out[((size_t)i * R_DIM + j) * CZ + z] = (pacc[mt][t] + bo) * recip[i * R_DIM + j];
            }
        }
    }
}

// ---------------------------------------------------------------------------
extern "C" void kernel_launch(void* const* d_in, const int* in_sizes, int n_in,
                              void* d_out, int out_size, void* d_ws, size_t ws_size,
                              hipStream_t stream)
{
    const float* m     = (const float*)d_in[0];
    const float* mask  = (const float*)d_in[1];
    const float* ln_s  = (const float*)d_in[2];
    const float* ln_b  = (const float*)d_in[3];
    const float* w1    = (const float*)d_in[4];
    const float* b1    = (const float*)d_in[5];
    const float* w2    = (const float*)d_in[6];
    const float* b2    = (const float*)d_in[7];
    const float* w_out = (const float*)d_in[8];
    const float* b_out = (const float*)d_in[9];
    float* out = (float*)d_out;

    char* ws = (char*)d_ws;
    __hip_bfloat16* a_t  = (__hip_bfloat16*)(ws);                                   // 2 MB
    __hip_bfloat16* b_t  = (__hip_bfloat16*)(ws + (size_t)(2u << 20));              // 2 MB
    __hip_bfloat16* wT   = (__hip_bfloat16*)(ws + (size_t)(4u << 20));              // 256 KB
    float*          rcp  = (float*)(ws + (size_t)(4u << 20) + (size_t)(256u << 10)); // 256 KB
    __hip_bfloat16* w12T = (__hip_bfloat16*)(ws + (size_t)(4u << 20) + (size_t)(512u << 10)); // 32 KB

    w12t_kernel<<<64, 256, 0, stream>>>(w1, w2, w12T);
    wt_kernel<<<512, 256, 0, stream>>>(w_out, wT);
    norm_kernel<<<R_DIM, R_DIM, 0, stream>>>(mask, rcp);
    ln_proj_kernel<<<1024, 256, 0, stream>>>(m, mask, ln_s, ln_b, w12T, b1, b2, a_t, b_t);
    fused_kernel<<<dim3(32, 32), 512, 0, stream>>>(a_t, b_t, wT, b_out, rcp, out);
}